// Round 1
// baseline (328.617 us; speedup 1.0000x reference)
//
#include <hip/hip_runtime.h>
#include <stdint.h>

#define B_   16
#define S_   1024
#define N_   4096
#define C_   768
#define OUT_ 256

typedef short bf16x8 __attribute__((ext_vector_type(8)));
typedef short bf16x4 __attribute__((ext_vector_type(4)));
typedef float f32x4  __attribute__((ext_vector_type(4)));

__device__ __forceinline__ unsigned short f2bf(float f) {
    unsigned int u = __float_as_uint(f);
    u += 0x7fffu + ((u >> 16) & 1u);   // round-to-nearest-even
    return (unsigned short)(u >> 16);
}

// ---------------------------------------------------------------------------
// K0: W fp32 -> bf16
// ---------------------------------------------------------------------------
__global__ __launch_bounds__(256) void k_wconv(const float* __restrict__ W,
                                               unsigned short* __restrict__ Wb) {
    int i = blockIdx.x * 256 + threadIdx.x;
    Wb[i] = f2bf(W[i]);
}

// ---------------------------------------------------------------------------
// K1: argmin_n d2(s,n).  Reference fp32 op order: ((s2 - 2*dot) + p2).
// UNCHANGED (numerics must match reference argmin exactly).
// ---------------------------------------------------------------------------
__global__ __launch_bounds__(256) void k_argmin(const float* __restrict__ seed,
                                                const float* __restrict__ pl,
                                                int* __restrict__ idx_out) {
    const int t    = threadIdx.x;
    const int lane = t & 63;
    const int w    = t >> 6;
    const int gw   = blockIdx.x * 4 + w;
    const int b    = gw >> 8;
    const int s0   = (gw & 255) * 4;

    float sx[4], sy[4], sz[4], s2[4], best[4];
    int   bidx[4];
#pragma unroll
    for (int j = 0; j < 4; ++j) {
        const float* sp = seed + (size_t)(b * S_ + s0 + j) * 3;
        sx[j] = sp[0]; sy[j] = sp[1]; sz[j] = sp[2];
        s2[j] = __fadd_rn(__fadd_rn(__fmul_rn(sx[j], sx[j]),
                                    __fmul_rn(sy[j], sy[j])),
                          __fmul_rn(sz[j], sz[j]));
        best[j] = 3.4e38f;
        bidx[j] = 0;
    }
    const float* pb = pl + (size_t)b * N_ * 3;

    for (int k = 0; k < N_ / 64; ++k) {
        const int   n  = k * 64 + lane;
        const float px = pb[n * 3 + 0];
        const float py = pb[n * 3 + 1];
        const float pz = pb[n * 3 + 2];
        const float p2 = __fadd_rn(__fadd_rn(__fmul_rn(px, px),
                                             __fmul_rn(py, py)),
                                   __fmul_rn(pz, pz));
#pragma unroll
        for (int j = 0; j < 4; ++j) {
            float dot = __fadd_rn(__fadd_rn(__fmul_rn(sx[j], px),
                                            __fmul_rn(sy[j], py)),
                                  __fmul_rn(sz[j], pz));
            float d2  = __fadd_rn(__fsub_rn(s2[j], __fmul_rn(2.0f, dot)), p2);
            if (d2 < best[j]) { best[j] = d2; bidx[j] = n; }
        }
    }

#pragma unroll
    for (int j = 0; j < 4; ++j) {
#pragma unroll
        for (int off = 32; off >= 1; off >>= 1) {
            float ob = __shfl_xor(best[j], off, 64);
            int   oi = __shfl_xor(bidx[j], off, 64);
            bool take = (ob < best[j]) || (ob == best[j] && oi < bidx[j]);
            if (take) { best[j] = ob; bidx[j] = oi; }
        }
        if (lane == 0) idx_out[b * S_ + s0 + j] = bidx[j];
    }
}

// ---------------------------------------------------------------------------
// K2 (ROUND 5): P[b][n][o] = bf16( sum_c f[b][c][n] * Wb[o][c] )  for ALL n.
// Restructured: reg-staged BOTH operands, double-buffered LDS, ONE barrier
// per K-step, prefetch-ahead-1 (issue next tile's global loads before the
// MFMA of the current tile; convert+ds_write after). ldsW rows padded to
// 40 shorts (80 B -> bank stride 20 dwords -> <=2-way, free; 16B aligned)
// fixing the previous 8-way conflict on every bF ds_read_b128.
// LDS: 2*(128*36 + 256*40)*2B = 59392 B -> 2 blocks/CU.
// ---------------------------------------------------------------------------
__global__ __launch_bounds__(256, 2) void k_pgemm(const float* __restrict__ f,
                                                  const unsigned short* __restrict__ Wb,
                                                  unsigned short* __restrict__ P) {
    __shared__ unsigned short ldsF[2][128 * 36];   // [n][k], row pad 36 (72 B)
    __shared__ unsigned short ldsW[2][256 * 40];   // [o][k], row pad 40 (80 B)
    const int t    = threadIdx.x;
    const int b    = blockIdx.x >> 5;
    const int nt   = blockIdx.x & 31;
    const int n0   = nt * 128;
    const int lane = t & 63;
    const int w    = t >> 6;
    const int wm   = w & 1;           // n-half (0..1) -> 64 rows
    const int wo   = w >> 1;          // o-half (0..1) -> 128 cols
    const int quad = lane >> 4, l16 = lane & 15;

    f32x4 acc[4][8];
#pragma unroll
    for (int i = 0; i < 4; ++i)
#pragma unroll
        for (int j = 0; j < 8; ++j) acc[i][j] = (f32x4){0.f, 0.f, 0.f, 0.f};

    // f staging: thread owns a 4c x 4n block (in-register 4x4 transpose)
    const int cb = t >> 5;            // 0..7  (4-c block)
    const int nb = t & 31;            // 0..31 (4-n block)
    const float* fB = f + (size_t)b * C_ * N_ + n0 + nb * 4;
    // W staging: thread owns 4 rows (o = wr + i*64), 16B chunk wc within k-tile
    const int wr = t >> 2;            // 0..63
    const int wc = t & 3;             // 0..3
    const unsigned short* wSrc = Wb + (size_t)wr * C_ + wc * 8;

    f32x4  v[4];
    bf16x8 wv[4];

    // ---- prologue: load + stage k-tile 0 into buffer 0 ----
#pragma unroll
    for (int j = 0; j < 4; ++j)
        v[j] = *(const f32x4*)(fB + (size_t)(cb * 4 + j) * N_);
#pragma unroll
    for (int i = 0; i < 4; ++i)
        wv[i] = *(const bf16x8*)(wSrc + (size_t)i * 64 * C_);
#pragma unroll
    for (int i = 0; i < 4; ++i) {
        bf16x4 pk = {(short)f2bf(v[0][i]), (short)f2bf(v[1][i]),
                     (short)f2bf(v[2][i]), (short)f2bf(v[3][i])};
        *(bf16x4*)(&ldsF[0][(nb * 4 + i) * 36 + cb * 4]) = pk;
    }
#pragma unroll
    for (int i = 0; i < 4; ++i)
        *(bf16x8*)(&ldsW[0][(wr + i * 64) * 40 + wc * 8]) = wv[i];
    __syncthreads();

    // ---- main loop: read buf[kt&1], prefetch kt+1, write buf[(kt+1)&1] ----
#pragma unroll 2
    for (int kt = 0; kt < C_ / 32; ++kt) {
        const int rb = kt & 1;
        const unsigned short* fR = &ldsF[rb][0];
        const unsigned short* wR = &ldsW[rb][0];
        unsigned short* fW = &ldsF[rb ^ 1][0];
        unsigned short* wW = &ldsW[rb ^ 1][0];

        if (kt < C_ / 32 - 1) {       // issue next tile's global loads EARLY
            const int k1 = (kt + 1) * 32;
#pragma unroll
            for (int j = 0; j < 4; ++j)
                v[j] = *(const f32x4*)(fB + (size_t)(k1 + cb * 4 + j) * N_);
#pragma unroll
            for (int i = 0; i < 4; ++i)
                wv[i] = *(const bf16x8*)(wSrc + (size_t)i * 64 * C_ + k1);
        }

        // compute current tile (loads above stay in flight under this)
        bf16x8 aF[4], bF[8];
#pragma unroll
        for (int mi = 0; mi < 4; ++mi) {
            const unsigned short* p = fR + (wm * 64 + mi * 16 + l16) * 36 + quad * 8;
            bf16x4 lo = *(const bf16x4*)p;
            bf16x4 hi = *(const bf16x4*)(p + 4);
            aF[mi] = __builtin_shufflevector(lo, hi, 0, 1, 2, 3, 4, 5, 6, 7);
        }
#pragma unroll
        for (int oi = 0; oi < 8; ++oi)
            bF[oi] = *(const bf16x8*)(wR + (wo * 128 + oi * 16 + l16) * 40 + quad * 8);
#pragma unroll
        for (int mi = 0; mi < 4; ++mi)
#pragma unroll
            for (int oi = 0; oi < 8; ++oi)
                acc[mi][oi] = __builtin_amdgcn_mfma_f32_16x16x32_bf16(
                    aF[mi], bF[oi], acc[mi][oi], 0, 0, 0);

        if (kt < C_ / 32 - 1) {       // convert + LDS-write next tile LATE
#pragma unroll
            for (int i = 0; i < 4; ++i) {
                bf16x4 pk = {(short)f2bf(v[0][i]), (short)f2bf(v[1][i]),
                             (short)f2bf(v[2][i]), (short)f2bf(v[3][i])};
                *(bf16x4*)(fW + (nb * 4 + i) * 36 + cb * 4) = pk;
            }
#pragma unroll
            for (int i = 0; i < 4; ++i)
                *(bf16x8*)(wW + (wr + i * 64) * 40 + wc * 8) = wv[i];
        }
        __syncthreads();              // single barrier per K-step
    }

    // epilogue: D row = n (A side), col = o (B side); store bf16
    unsigned short* Pb = P + ((size_t)b * N_ + n0) * OUT_;
#pragma unroll
    for (int mi = 0; mi < 4; ++mi) {
#pragma unroll
        for (int r = 0; r < 4; ++r) {
            const int n = wm * 64 + mi * 16 + quad * 4 + r;
            unsigned short* row = Pb + (size_t)n * OUT_;
#pragma unroll
            for (int oi = 0; oi < 8; ++oi) {
                const int o = wo * 128 + oi * 16 + l16;
                row[o] = f2bf(acc[mi][oi][r]);
            }
        }
    }
}

// ---------------------------------------------------------------------------
// K3: out[b][o][s] = f32(P[b][idx[b][s]][o]) + bias[o]   (UNCHANGED)
// ---------------------------------------------------------------------------
__global__ __launch_bounds__(256) void k_out(const unsigned short* __restrict__ P,
                                             const int* __restrict__ idx,
                                             const float* __restrict__ bias,
                                             float* __restrict__ out) {
    __shared__ unsigned short tl[64 * 260];
    const int t  = threadIdx.x;
    const int b  = blockIdx.x >> 4;
    const int st = blockIdx.x & 15;
    const int s0 = st * 64;
    const unsigned short* Pb = P + (size_t)b * N_ * OUT_;

#pragma unroll
    for (int i = 0; i < 8; ++i) {
        const int g = i * 256 + t;
        const int s = g >> 5;            // 0..63
        const int p = g & 31;            // 16B chunk within 512B row
        const int n = idx[b * S_ + s0 + s];
        const unsigned short* src = Pb + (size_t)n * OUT_ + p * 8;
        uint2 u0 = *(const uint2*)src;
        uint2 u1 = *(const uint2*)(src + 4);
        *(uint2*)(tl + s * 260 + p * 8)     = u0;   // b64 writes (8B aligned)
        *(uint2*)(tl + s * 260 + p * 8 + 4) = u1;
    }
    __syncthreads();

    const int lane = t & 63;
    const int w    = t >> 6;
    float* ob = out + (size_t)b * OUT_ * S_ + s0;
#pragma unroll 4
    for (int oo = 0; oo < 64; ++oo) {
        const int o = w * 64 + oo;
        const unsigned short u = tl[lane * 260 + o];
        const float val = __uint_as_float(((unsigned int)u) << 16) + bias[o];
        ob[(size_t)o * S_ + lane] = val;
    }
}

// ---------------------------------------------------------------------------
// Workspace: [0,64K) idx int32[16][1024]
//            [64K,64K+384K) Wb bf16[256][768]
//            [512K, 512K+33.6MB) P bf16[16][4096][256]
// ---------------------------------------------------------------------------
extern "C" void kernel_launch(void* const* d_in, const int* in_sizes, int n_in,
                              void* d_out, int out_size, void* d_ws, size_t ws_size,
                              hipStream_t stream) {
    const float* seed = (const float*)d_in[0];   // [16,1024,3]
    const float* pl   = (const float*)d_in[1];   // [16,4096,3]
    const float* f    = (const float*)d_in[2];   // [16,768,4096]
    const float* W    = (const float*)d_in[3];   // [256,768]
    const float* bias = (const float*)d_in[4];   // [256]
    float* out = (float*)d_out;                  // [16,256,1024] fp32

    int* idx            = (int*)d_ws;
    unsigned short* Wb  = (unsigned short*)((char*)d_ws + 65536);
    unsigned short* P   = (unsigned short*)((char*)d_ws + 524288);

    k_wconv <<<768,  256, 0, stream>>>(W, Wb);
    k_argmin<<<1024, 256, 0, stream>>>(seed, pl, idx);
    k_pgemm <<<512,  256, 0, stream>>>(f, Wb, P);
    k_out   <<<256,  256, 0, stream>>>(P, idx, bias, out);
}